// Round 1
// baseline (62.261 us; speedup 1.0000x reference)
//
#include <hip/hip_runtime.h>

// BarrelShifter8: out[row][j] = (j >= k) ? P[row][j-k] : 0, k = 4*s2 + 2*s1 + s0.
// Derivation: mux(s,a,b) with binary inputs == (s ? a : b); shift_left(x,k)[j] =
// x[j-k] for j>=k else 0. Stages compose into one barrel shift by k bits.
// Memory-bound: 304 MiB total traffic -> target ~50 us at 6.3 TB/s.

__global__ __launch_bounds__(256) void barrel_shifter8_kernel(
    const float* __restrict__ P,   // (N, 8), values exactly 0.0f or 1.0f
    const float* __restrict__ S,   // (N, 3), values exactly 0.0f or 1.0f
    float*       __restrict__ out, // (N, 8)
    int N)
{
    int tid    = blockIdx.x * blockDim.x + threadIdx.x;
    int stride = gridDim.x * blockDim.x;

    for (int row = tid; row < N; row += stride) {
        // Coalesced 32 B row load as two float4.
        const float4* p4 = reinterpret_cast<const float4*>(P + (size_t)row * 8);
        float4 a = p4[0];
        float4 b = p4[1];

        // S row: 3 scalar loads; wave's 64 lanes cover a contiguous, fully-used span.
        const float* s = S + (size_t)row * 3;
        float s0 = s[0];
        float s1 = s[1];
        float s2 = s[2];

        int k = (s2 >= 0.5f ? 4 : 0) + (s1 >= 0.5f ? 2 : 0) + (s0 >= 0.5f ? 1 : 0);

        // Pack the 8 binary floats into bits; barrel shift; unpack with
        // compile-time-constant bit tests (no runtime-indexed reg array ->
        // no scratch spill, rule #20).
        unsigned bits =
            (a.x >= 0.5f ?   1u : 0u) | (a.y >= 0.5f ?   2u : 0u) |
            (a.z >= 0.5f ?   4u : 0u) | (a.w >= 0.5f ?   8u : 0u) |
            (b.x >= 0.5f ?  16u : 0u) | (b.y >= 0.5f ?  32u : 0u) |
            (b.z >= 0.5f ?  64u : 0u) | (b.w >= 0.5f ? 128u : 0u);

        unsigned sh = (bits << k) & 0xFFu;

        float4 o0, o1;
        o0.x = (sh &   1u) ? 1.0f : 0.0f;
        o0.y = (sh &   2u) ? 1.0f : 0.0f;
        o0.z = (sh &   4u) ? 1.0f : 0.0f;
        o0.w = (sh &   8u) ? 1.0f : 0.0f;
        o1.x = (sh &  16u) ? 1.0f : 0.0f;
        o1.y = (sh &  32u) ? 1.0f : 0.0f;
        o1.z = (sh &  64u) ? 1.0f : 0.0f;
        o1.w = (sh & 128u) ? 1.0f : 0.0f;

        float4* q4 = reinterpret_cast<float4*>(out + (size_t)row * 8);
        q4[0] = o0;
        q4[1] = o1;
    }
}

extern "C" void kernel_launch(void* const* d_in, const int* in_sizes, int n_in,
                              void* d_out, int out_size, void* d_ws, size_t ws_size,
                              hipStream_t stream) {
    const float* P = (const float*)d_in[0];
    const float* S = (const float*)d_in[1];
    float* out = (float*)d_out;

    int N = in_sizes[0] / 8;  // rows

    const int block = 256;
    int needed = (N + block - 1) / block;
    int grid = needed < 2048 ? needed : 2048;  // memory-bound: cap + grid-stride

    barrel_shifter8_kernel<<<grid, block, 0, stream>>>(P, S, out, N);
}